// Round 18
// baseline (364.121 us; speedup 1.0000x reference)
//
#include <hip/hip_runtime.h>
#include <hip/hip_bf16.h>
#include <stdint.h>

#define BB 8
#define NN 2048

// ---- workspace layout ----
#define OFF_B1 272
#define OFF_B2 4432
#define OFF_B3 12688
#define T_BASE   (65536 + 2*1024*1024)
#define T1_OFF   T_BASE               // [64][32] bf16, 4096 B (stays in L2)
#define T2H_OFF  (T1_OFF + 4096)      // [64][72] bf16, K-permuted
#define T2L_OFF  (T2H_OFF + 9216)
#define T3H_OFF  (T2L_OFF + 9216)     // [128][72] bf16, K-permuted
#define T3L_OFF  (T3H_OFF + 18432)
// fused-kernel LDS: staged T2/T3 (55296 B) + 8 wave-private survivor slots (4096 B)
#define LF_T2H   0                    // half-offsets
#define LF_T2L   4608
#define LF_T3H   9216
#define LF_T3L   18432
#define LF_TABLE_BYTES 55296          // 3456 uint4
#define LF_SLOT_BYTES  4096           // 8 waves x 64 x u64

typedef __attribute__((ext_vector_type(4))) float f32x4;
typedef __attribute__((ext_vector_type(8))) short s16x8;

__device__ __forceinline__ float ldany(const void* p, long i, int isf32) {
    if (isf32) return ((const float*)p)[i];
    uint32_t u = ((uint32_t)((const uint16_t*)p)[i]) << 16;
    float f; __builtin_memcpy(&f, &u, 4); return f;
}
__device__ __forceinline__ uint16_t f2bf(float f) {
    uint32_t u; __builtin_memcpy(&u, &f, 4);
    return (uint16_t)((u + 0x7FFFu + ((u >> 16) & 1u)) >> 16);
}
__device__ __forceinline__ float bf2f(uint16_t h) {
    uint32_t u = ((uint32_t)h) << 16;
    float f; __builtin_memcpy(&f, &u, 4); return f;
}
__device__ __forceinline__ uint32_t pk2(float a, float b) {
    __hip_bfloat162 h = __float22bfloat162_rn(make_float2(a, b));
    uint32_t u; __builtin_memcpy(&u, &h, 4); return u;
}
__device__ __forceinline__ s16x8 mk8(uint32_t a, uint32_t b, uint32_t c, uint32_t d) {
    uint32_t t[4] = {a, b, c, d}; s16x8 r; __builtin_memcpy(&r, t, 16); return r;
}
__device__ __forceinline__ float sane(float v) {
    return (v == v && v > -1e30f && v < 1e30f) ? v : 0.f;
}
__device__ __forceinline__ int mbcnt64(unsigned long long m) {
    return __builtin_amdgcn_mbcnt_hi((uint32_t)(m >> 32),
           __builtin_amdgcn_mbcnt_lo((uint32_t)m, 0));
}
__device__ __forceinline__ int kperm_pos(int kk) {
    int g = kk >> 5, c5 = kk & 31;
    int sub = (c5 >> 4) & 1, q = (c5 >> 2) & 3, r = c5 & 3;
    return 32 * g + 8 * q + 4 * sub + r;
}

// ---------------- K0: parallel dtype detect + fold + padded K-permuted tables (R11-proven) ----------------
__global__ void k0_fold(const void* p1,
                        const void* W1, const void* b1, const void* g1, const void* be1, const void* m1, const void* v1,
                        const void* W2, const void* b2, const void* g2, const void* be2, const void* m2, const void* v2,
                        const void* W3, const void* b3, const void* g3, const void* be3, const void* m3, const void* v3,
                        float* wsf, int* wsi) {
    __shared__ int s_cnt;
    int t = threadIdx.x;
    if (t == 0) s_cnt = 0;
    __syncthreads();
    const uint16_t* u = (const uint16_t*)p1;
    int c = 0;
    for (int i = t; i < 4096; i += 256) {
        uint16_t x = u[i];
        uint32_t e = (x >> 7) & 0xFF;
        c += ((e >= 0x70 && e <= 0x84) || x == 0) ? 1 : 0;
    }
    atomicAdd(&s_cnt, c);
    __syncthreads();
    int isf32 = (s_cnt < 3686) ? 1 : 0;
    if (blockIdx.x == 0 && t == 0) wsi[0] = isf32;

    uint16_t* t1  = (uint16_t*)((char*)wsf + T1_OFF);
    uint16_t* t2h = (uint16_t*)((char*)wsf + T2H_OFF);
    uint16_t* t2l = (uint16_t*)((char*)wsf + T2L_OFF);
    uint16_t* t3h = (uint16_t*)((char*)wsf + T3H_OFF);
    uint16_t* t3l = (uint16_t*)((char*)wsf + T3L_OFF);

    int gid = blockIdx.x * 256 + t;
    if (gid < 4096) {
        int o = gid >> 6, kk = gid & 63;
        float s = ldany(g2, o, isf32) * rsqrtf(ldany(v2, o, isf32) + 1e-3f);
        float w = ldany(W2, gid, isf32) * s;
        uint16_t wh = f2bf(w);
        int pos = o * 72 + kperm_pos(kk);
        t2h[pos] = wh; t2l[pos] = f2bf(w - bf2f(wh));
    } else if (gid < 12288) {
        int e = gid - 4096;
        int o = e >> 6, kk = e & 63;
        float s = ldany(g3, o, isf32) * rsqrtf(ldany(v3, o, isf32) + 1e-3f);
        float w = ldany(W3, e, isf32) * s;
        uint16_t wh = f2bf(w);
        int pos = o * 72 + kperm_pos(kk);
        t3h[pos] = wh; t3l[pos] = f2bf(w - bf2f(wh));
    } else if (gid < 12544) {
        int e = gid - 12288;
        int co = e >> 2, cc = e & 3;
        float s = ldany(g1, co, isf32) * rsqrtf(ldany(v1, co, isf32) + 1e-3f);
        float w = ldany(W1, co*4 + cc, isf32) * s;
        uint16_t wh = f2bf(w), wl = f2bf(w - bf2f(wh));
        t1[co*32 + cc]     = wh;
        t1[co*32 + 4 + cc] = wh;
        t1[co*32 + 8 + cc] = wl;
    } else if (gid < 13824) {
        int e = gid - 12544;
        int co = e / 20, k = e - co * 20;
        t1[co*32 + 12 + k] = 0;
    } else if (gid < 13888) {
        int o = gid - 13824;
        float s = ldany(g1, o, isf32) * rsqrtf(ldany(v1, o, isf32) + 1e-3f);
        wsf[OFF_B1 + o] = (ldany(b1, o, isf32) - ldany(m1, o, isf32)) * s + ldany(be1, o, isf32);
    } else if (gid < 13952) {
        int o = gid - 13888;
        float s = ldany(g2, o, isf32) * rsqrtf(ldany(v2, o, isf32) + 1e-3f);
        wsf[OFF_B2 + o] = (ldany(b2, o, isf32) - ldany(m2, o, isf32)) * s + ldany(be2, o, isf32);
    } else if (gid < 14080) {
        int o = gid - 13952;
        float s = ldany(g3, o, isf32) * rsqrtf(ldany(v3, o, isf32) + 1e-3f);
        wsf[OFF_B3 + o] = (ldany(b3, o, isf32) - ldany(m3, o, isf32)) * s + ldany(be3, o, isf32);
    }
}

// ---- one-target exact top-32 (R16-proven): 32 cands, windowed bisect, scatter, sort; returns sorted key ----
__device__ __forceinline__ unsigned long long knn_target(const void* p, long base, int isf32, int lane,
                                                         float qx, float qy, float qz, float s1,
                                                         unsigned long long* sl) {
    uint32_t kb[32];
    if (!isf32) {
        const uint16_t* tpu = (const uint16_t*)p + base;
        const uint4* rx = (const uint4*)(tpu);
        const uint4* ry = (const uint4*)(tpu + NN);
        const uint4* rz = (const uint4*)(tpu + 2*NN);
        #pragma unroll
        for (int i = 0; i < 4; i++) {
            int v4 = i * 64 + lane;
            uint4 X = rx[v4], Y = ry[v4], Z = rz[v4];
            uint32_t xw[4] = {X.x, X.y, X.z, X.w};
            uint32_t yw[4] = {Y.x, Y.y, Y.z, Y.w};
            uint32_t zw[4] = {Z.x, Z.y, Z.z, Z.w};
            #pragma unroll
            for (int j = 0; j < 4; j++) {
                #pragma unroll
                for (int w = 0; w < 2; w++) {
                    uint32_t ux = (w == 0) ? (xw[j] << 16) : (xw[j] & 0xFFFF0000u);
                    uint32_t uy = (w == 0) ? (yw[j] << 16) : (yw[j] & 0xFFFF0000u);
                    uint32_t uz = (w == 0) ? (zw[j] << 16) : (zw[j] & 0xFFFF0000u);
                    float nx, ny, nz;
                    __builtin_memcpy(&nx, &ux, 4); __builtin_memcpy(&ny, &uy, 4); __builtin_memcpy(&nz, &uz, 4);
                    float s2  = nx * nx + ny * ny + nz * nz;
                    float dot = qx * nx + qy * ny + qz * nz;
                    float d2  = fmaxf((s1 + s2) - 2.0f * dot, 0.0f);
                    uint32_t bits; __builtin_memcpy(&bits, &d2, 4);
                    kb[i*8 + j*2 + w] = bits;
                }
            }
        }
    } else {
        const float* tpf = (const float*)p + base;
        #pragma unroll
        for (int i = 0; i < 32; i++) {
            int j = i * 64 + lane;
            float nx = tpf[j];
            float ny = tpf[NN + j];
            float nz = tpf[2*NN + j];
            float s2  = nx * nx + ny * ny + nz * nz;
            float dot = qx * nx + qy * ny + qz * nz;
            float d2  = fmaxf((s1 + s2) - 2.0f * dot, 0.0f);
            uint32_t bits; __builtin_memcpy(&bits, &d2, 4);
            kb[i] = bits;
        }
    }

    uint32_t lo = 0u, hi = 0x7F800001u, tau = 0u;
    while (true) {
        uint32_t mid = lo + ((hi - lo) >> 1);
        int c = 0;
        #pragma unroll
        for (int i = 0; i < 32; i++) c += __builtin_popcountll(__ballot(kb[i] < mid));
        if (c < 32)      lo = mid;
        else if (c > 64) hi = mid;
        else { tau = mid; break; }
        if (hi - lo <= 1u) { tau = hi; break; }
    }

    sl[lane] = ~0ull;
    int basePos = 0;
    #pragma unroll
    for (int i = 0; i < 32; i++) {
        unsigned idxv = isf32 ? (unsigned)(i * 64 + lane)
                              : (unsigned)((i >> 3) * 512 + 8 * lane + (i & 7));
        bool pz = kb[i] < tau;
        unsigned long long m = __ballot(pz);
        int pos = basePos + mbcnt64(m);
        if (pz && pos < 64) sl[pos] = (((unsigned long long)kb[i]) << 32) | idxv;
        basePos += __builtin_popcountll(m);
    }
    unsigned long long key = sl[lane];

    #pragma unroll
    for (int sz = 2; sz <= 64; sz <<= 1) {
        #pragma unroll
        for (int st = sz >> 1; st > 0; st >>= 1) {
            unsigned long long ot = __shfl_xor(key, st, 64);
            bool up    = ((lane & sz) == 0);
            bool lower = ((lane & st) == 0);
            unsigned long long mn = (key < ot) ? key : ot;
            unsigned long long mx = (key < ot) ? ot : key;
            key = (lower == up) ? mn : mx;
        }
    }
    return key;
}

// ---------------- K12: fused KNN (sequential phases) + MFMA MLP, register handoff ----------------
// 512 threads = 8 waves. LDS: 55296 B staged T2/T3 + 4096 B survivor slots = 59392 B -> 2 blocks/CU,
// VGPR ~112-128 -> 4 waves/SIMD -> 16 waves/CU across 2 drifting blocks (KNN VALU / MLP MFMA overlap).
__launch_bounds__(512)
__global__ void k12_fused(const void* p1, const void* p2, const float* __restrict__ wsf, const int* wsi,
                          void* outp) {
    __shared__ uint4 shmem4[(LF_TABLE_BYTES + LF_SLOT_BYTES) / 16];

    // stage T2/T3 (contiguous in ws) -> LDS
    {
        const uint4* src = (const uint4*)((const char*)wsf + T2H_OFF);
        for (int i = threadIdx.x; i < LF_TABLE_BYTES / 16; i += 512) shmem4[i] = src[i];
    }
    __syncthreads();
    const uint16_t* shw = (const uint16_t*)shmem4;
    const uint16_t* T2H = shw + LF_T2H;
    const uint16_t* T2L = shw + LF_T2L;
    const uint16_t* T3H = shw + LF_T3H;
    const uint16_t* T3L = shw + LF_T3L;
    const uint16_t* T1  = (const uint16_t*)((const char*)wsf + T1_OFF);   // L2 (4 loads/wave)

    int isf32 = wsi[0];
    int lane = threadIdx.x & 63;
    int wave = threadIdx.x >> 6;          // 0..7
    int qidx = blockIdx.x * 8 + wave;     // 2048 blocks x 8 waves = 16384 queries
    int b = qidx >> 11, n = qidx & 2047;
    long base = (long)b * 3 * NN;

    float qx = sane(ldany(p1, base + n,        isf32));
    float qy = sane(ldany(p1, base + NN + n,   isf32));
    float qz = sane(ldany(p1, base + 2*NN + n, isf32));
    float s1 = qx * qx + qy * qy + qz * qz;

    unsigned long long* sl = (unsigned long long*)((char*)shmem4 + LF_TABLE_BYTES) + wave * 64;

    // ---- KNN phase A (p1), then B (p2) — R16-proven sequential structure ----
    unsigned long long keyA = knn_target(p1, base, isf32, lane, qx, qy, qz, s1, sl);
    __builtin_amdgcn_sched_barrier(0);
    asm volatile("" ::: "memory");
    unsigned long long keyB = knn_target(p2, base, isf32, lane, qx, qy, qz, s1, sl);

    // ---- register handoff (R7-proven): lane<32 -> tgt0 rank=lane; lane>=32 -> tgt1 rank=lane-32 ----
    uint32_t loA = (uint32_t)keyA;
    uint32_t loB = (uint32_t)keyB;
    int srcl = (lane >= 32) ? (lane - 32) : lane;
    uint32_t iB = (uint32_t)__shfl((int)loB, srcl, 64);
    int idx = (int)(((lane < 32) ? loA : iB) & 2047u);

    // ================= MLP (verbatim R17 k2 from gather onward) =================
    int c = lane & 15;
    int q = lane >> 4;

    const void* sp = (lane < 32) ? p1 : p2;
    float nx = sane(ldany(sp, base + idx,        isf32));
    float ny = sane(ldany(sp, base + NN + idx,   isf32));
    float nz = sane(ldany(sp, base + 2*NN + idx, isf32));

    float r0 = nx - qx, r1 = ny - qy, r2 = nz - qz;
    float ss = fmaf(r0, r0, fmaf(r1, r1, r2 * r2));
    float dist = sqrtf(fmaxf(ss, 1e-12f));

    const float* B1 = wsf + OFF_B1;
    const float* B2 = wsf + OFF_B2;
    const float* B3 = wsf + OFF_B3;

    s16x8 b1f[4];
    #pragma unroll
    for (int nt = 0; nt < 4; nt++) {
        int src = 16 * nt + c;
        float f0 = __shfl(r0, src, 64);
        float f1 = __shfl(r1, src, 64);
        float f2v = __shfl(r2, src, 64);
        float f3v = __shfl(dist, src, 64);
        uint16_t h0 = f2bf(f0), h1 = f2bf(f1), h2 = f2bf(f2v), h3 = f2bf(f3v);
        uint16_t l0 = f2bf(f0 - bf2f(h0)), l1 = f2bf(f1 - bf2f(h1));
        uint16_t l2 = f2bf(f2v - bf2f(h2)), l3 = f2bf(f3v - bf2f(h3));
        s16x8 v;
        bool qa = (q < 2);
        bool qb = (q == 0);
        v[0] = qa ? (short)h0 : (short)0;
        v[1] = qa ? (short)h1 : (short)0;
        v[2] = qa ? (short)h2 : (short)0;
        v[3] = qa ? (short)h3 : (short)0;
        v[4] = qb ? (short)l0 : (short)0;
        v[5] = qb ? (short)l1 : (short)0;
        v[6] = qb ? (short)l2 : (short)0;
        v[7] = qb ? (short)l3 : (short)0;
        b1f[nt] = v;
    }

    f32x4 d1[4][4];
    #pragma unroll
    for (int mt = 0; mt < 4; mt++) {
        s16x8 a1 = *(const s16x8*)(T1 + (16 * mt + c) * 32 + q * 8);
        f32x4 bias = *(const f32x4*)(B1 + 16 * mt + 4 * q);
        #pragma unroll
        for (int nt = 0; nt < 4; nt++) {
            d1[mt][nt] = __builtin_amdgcn_mfma_f32_16x16x32_bf16(a1, b1f[nt], bias, 0, 0, 0);
        }
    }

    auto mkfrag = [](const f32x4& dlo, const f32x4& dhi) -> s16x8 {
        return mk8(pk2(fmaxf(dlo[0], 0.f), fmaxf(dlo[1], 0.f)),
                   pk2(fmaxf(dlo[2], 0.f), fmaxf(dlo[3], 0.f)),
                   pk2(fmaxf(dhi[0], 0.f), fmaxf(dhi[1], 0.f)),
                   pk2(fmaxf(dhi[2], 0.f), fmaxf(dhi[3], 0.f)));
    };

    f32x4 d2[4][4];
    #pragma unroll
    for (int mt = 0; mt < 4; mt++) {
        f32x4 bias = *(const f32x4*)(B2 + 16 * mt + 4 * q);
        #pragma unroll
        for (int nt = 0; nt < 4; nt++) d2[mt][nt] = bias;
    }
    #pragma unroll
    for (int g = 0; g < 2; g++) {
        s16x8 fh[4];
        #pragma unroll
        for (int nt = 0; nt < 4; nt++) fh[nt] = mkfrag(d1[2*g][nt], d1[2*g+1][nt]);
        #pragma unroll
        for (int mt = 0; mt < 4; mt++) {
            s16x8 ah = *(const s16x8*)(T2H + (16 * mt + c) * 72 + 32 * g + 8 * q);
            s16x8 al = *(const s16x8*)(T2L + (16 * mt + c) * 72 + 32 * g + 8 * q);
            #pragma unroll
            for (int nt = 0; nt < 4; nt++) {
                f32x4 acc = d2[mt][nt];
                acc = __builtin_amdgcn_mfma_f32_16x16x32_bf16(ah, fh[nt], acc, 0, 0, 0);
                acc = __builtin_amdgcn_mfma_f32_16x16x32_bf16(al, fh[nt], acc, 0, 0, 0);
                d2[mt][nt] = acc;
            }
        }
    }

    s16x8 f3h[2][4];
    #pragma unroll
    for (int g = 0; g < 2; g++)
        #pragma unroll
        for (int nt = 0; nt < 4; nt++) f3h[g][nt] = mkfrag(d2[2*g][nt], d2[2*g+1][nt]);

    float mx[4] = {-1e30f, -1e30f, -1e30f, -1e30f};
    #pragma unroll
    for (int mt = 0; mt < 8; mt++) {
        f32x4 bias = *(const f32x4*)(B3 + 16 * mt + 4 * q);
        f32x4 acc[4];
        #pragma unroll
        for (int nt = 0; nt < 4; nt++) acc[nt] = bias;
        #pragma unroll
        for (int g = 0; g < 2; g++) {
            s16x8 ah = *(const s16x8*)(T3H + (16 * mt + c) * 72 + 32 * g + 8 * q);
            s16x8 al = *(const s16x8*)(T3L + (16 * mt + c) * 72 + 32 * g + 8 * q);
            #pragma unroll
            for (int nt = 0; nt < 4; nt++) {
                f32x4 a = acc[nt];
                a = __builtin_amdgcn_mfma_f32_16x16x32_bf16(ah, f3h[g][nt], a, 0, 0, 0);
                a = __builtin_amdgcn_mfma_f32_16x16x32_bf16(al, f3h[g][nt], a, 0, 0, 0);
                acc[nt] = a;
            }
        }
        #pragma unroll
        for (int nt = 0; nt < 4; nt++) {
            mx[nt] = fmaxf(mx[nt], fmaxf(fmaxf(acc[nt][0], acc[nt][1]), fmaxf(acc[nt][2], acc[nt][3])));
        }
    }

    #pragma unroll
    for (int nt = 0; nt < 4; nt++) {
        mx[nt] = fmaxf(mx[nt], __shfl_xor(mx[nt], 16, 64));
        mx[nt] = fmaxf(mx[nt], __shfl_xor(mx[nt], 32, 64));
        mx[nt] = fmaxf(mx[nt], 0.f);
    }
    float mall = fmaxf(fmaxf(mx[0], mx[1]), fmaxf(mx[2], mx[3]));
    #pragma unroll
    for (int m = 1; m < 16; m <<= 1) mall = fmaxf(mall, __shfl_xor(mall, m, 64));
    float e0 = __expf(mx[0] - mall), e1 = __expf(mx[1] - mall);
    float e2 = __expf(mx[2] - mall), e3 = __expf(mx[3] - mall);
    float s = e0 + e1 + e2 + e3;
    #pragma unroll
    for (int m = 1; m < 16; m <<= 1) s += __shfl_xor(s, m, 64);
    float eown = (q == 0) ? e0 : (q == 1) ? e1 : (q == 2) ? e2 : e3;
    float w = eown / s;

    float sx = w * nx, sy = w * ny, sz = w * nz;
    #pragma unroll
    for (int m = 1; m < 64; m <<= 1) {
        sx += __shfl_xor(sx, m, 64);
        sy += __shfl_xor(sy, m, 64);
        sz += __shfl_xor(sz, m, 64);
    }

    if (lane < 3) {
        float v = (lane == 0) ? sx : ((lane == 1) ? sy : sz);
        long oi = base + (long)lane * NN + n;
        if (isf32) {
            ((float*)outp)[oi] = v;
        } else {
            ((uint16_t*)outp)[oi] = f2bf(v);
        }
    }
}

extern "C" void kernel_launch(void* const* d_in, const int* in_sizes, int n_in,
                              void* d_out, int out_size, void* d_ws, size_t ws_size,
                              hipStream_t stream) {
    const void* p1 = d_in[0];
    const void* p2 = d_in[1];
    float* wsf = (float*)d_ws;
    int*   wsi = (int*)d_ws;

    k0_fold<<<64, 256, 0, stream>>>(p1,
        d_in[2],  d_in[3],  d_in[4],  d_in[5],  d_in[6],  d_in[7],
        d_in[8],  d_in[9],  d_in[10], d_in[11], d_in[12], d_in[13],
        d_in[14], d_in[15], d_in[16], d_in[17], d_in[18], d_in[19],
        wsf, wsi);

    // 8 waves/block, one query per wave: 2048 blocks x 8 = 16384 queries
    k12_fused<<<(BB * NN) / 8, 512, 0, stream>>>(p1, p2, wsf, wsi, d_out);
}

// Round 19
// 259.511 us; speedup vs baseline: 1.4031x; 1.4031x over previous
//
#include <hip/hip_runtime.h>
#include <hip/hip_bf16.h>
#include <stdint.h>

#define BB 8
#define NN 2048

// ---- workspace layout ----
#define OFF_B1 272
#define OFF_B2 4432
#define OFF_B3 12688
#define IDX_BYTE_OFF 65536            // u16 idx[B][N][64] = 2 MiB
#define T_BASE   (65536 + 2*1024*1024)
#define T1_OFF   T_BASE               // [64][32] bf16, 4096 B
#define T2H_OFF  (T1_OFF + 4096)      // [64][72] bf16, K-permuted
#define T2L_OFF  (T2H_OFF + 9216)
#define T3H_OFF  (T2L_OFF + 9216)     // [128][72] bf16, K-permuted
#define T3L_OFF  (T3H_OFF + 18432)
// LDS half-offsets for k2's staged copy (full table block)
#define L_T1   0
#define L_T2H  2048
#define L_T2L  6656
#define L_T3H  11264
#define L_T3L  20480
#define L_HALVES 29696                // 59392 B = 3712 uint4

typedef __attribute__((ext_vector_type(4))) float f32x4;
typedef __attribute__((ext_vector_type(8))) short s16x8;

__device__ __forceinline__ float ldany(const void* p, long i, int isf32) {
    if (isf32) return ((const float*)p)[i];
    uint32_t u = ((uint32_t)((const uint16_t*)p)[i]) << 16;
    float f; __builtin_memcpy(&f, &u, 4); return f;
}
__device__ __forceinline__ uint16_t f2bf(float f) {
    uint32_t u; __builtin_memcpy(&u, &f, 4);
    return (uint16_t)((u + 0x7FFFu + ((u >> 16) & 1u)) >> 16);
}
__device__ __forceinline__ float bf2f(uint16_t h) {
    uint32_t u = ((uint32_t)h) << 16;
    float f; __builtin_memcpy(&f, &u, 4); return f;
}
__device__ __forceinline__ uint32_t pk2(float a, float b) {
    __hip_bfloat162 h = __float22bfloat162_rn(make_float2(a, b));
    uint32_t u; __builtin_memcpy(&u, &h, 4); return u;
}
__device__ __forceinline__ s16x8 mk8(uint32_t a, uint32_t b, uint32_t c, uint32_t d) {
    uint32_t t[4] = {a, b, c, d}; s16x8 r; __builtin_memcpy(&r, t, 16); return r;
}
__device__ __forceinline__ float sane(float v) {
    return (v == v && v > -1e30f && v < 1e30f) ? v : 0.f;
}
__device__ __forceinline__ int mbcnt64(unsigned long long m) {
    return __builtin_amdgcn_mbcnt_hi((uint32_t)(m >> 32),
           __builtin_amdgcn_mbcnt_lo((uint32_t)m, 0));
}
__device__ __forceinline__ int kperm_pos(int kk) {
    int g = kk >> 5, c5 = kk & 31;
    int sub = (c5 >> 4) & 1, q = (c5 >> 2) & 3, r = c5 & 3;
    return 32 * g + 8 * q + 4 * sub + r;
}

// ---------------- K0: parallel dtype detect + fold + padded K-permuted tables (R11-proven) ----------------
__global__ void k0_fold(const void* p1,
                        const void* W1, const void* b1, const void* g1, const void* be1, const void* m1, const void* v1,
                        const void* W2, const void* b2, const void* g2, const void* be2, const void* m2, const void* v2,
                        const void* W3, const void* b3, const void* g3, const void* be3, const void* m3, const void* v3,
                        float* wsf, int* wsi) {
    __shared__ int s_cnt;
    int t = threadIdx.x;
    if (t == 0) s_cnt = 0;
    __syncthreads();
    const uint16_t* u = (const uint16_t*)p1;
    int c = 0;
    for (int i = t; i < 4096; i += 256) {
        uint16_t x = u[i];
        uint32_t e = (x >> 7) & 0xFF;
        c += ((e >= 0x70 && e <= 0x84) || x == 0) ? 1 : 0;
    }
    atomicAdd(&s_cnt, c);
    __syncthreads();
    int isf32 = (s_cnt < 3686) ? 1 : 0;
    if (blockIdx.x == 0 && t == 0) wsi[0] = isf32;

    uint16_t* t1  = (uint16_t*)((char*)wsf + T1_OFF);
    uint16_t* t2h = (uint16_t*)((char*)wsf + T2H_OFF);
    uint16_t* t2l = (uint16_t*)((char*)wsf + T2L_OFF);
    uint16_t* t3h = (uint16_t*)((char*)wsf + T3H_OFF);
    uint16_t* t3l = (uint16_t*)((char*)wsf + T3L_OFF);

    int gid = blockIdx.x * 256 + t;
    if (gid < 4096) {
        int o = gid >> 6, kk = gid & 63;
        float s = ldany(g2, o, isf32) * rsqrtf(ldany(v2, o, isf32) + 1e-3f);
        float w = ldany(W2, gid, isf32) * s;
        uint16_t wh = f2bf(w);
        int pos = o * 72 + kperm_pos(kk);
        t2h[pos] = wh; t2l[pos] = f2bf(w - bf2f(wh));
    } else if (gid < 12288) {
        int e = gid - 4096;
        int o = e >> 6, kk = e & 63;
        float s = ldany(g3, o, isf32) * rsqrtf(ldany(v3, o, isf32) + 1e-3f);
        float w = ldany(W3, e, isf32) * s;
        uint16_t wh = f2bf(w);
        int pos = o * 72 + kperm_pos(kk);
        t3h[pos] = wh; t3l[pos] = f2bf(w - bf2f(wh));
    } else if (gid < 12544) {
        int e = gid - 12288;
        int co = e >> 2, cc = e & 3;
        float s = ldany(g1, co, isf32) * rsqrtf(ldany(v1, co, isf32) + 1e-3f);
        float w = ldany(W1, co*4 + cc, isf32) * s;
        uint16_t wh = f2bf(w), wl = f2bf(w - bf2f(wh));
        t1[co*32 + cc]     = wh;
        t1[co*32 + 4 + cc] = wh;
        t1[co*32 + 8 + cc] = wl;
    } else if (gid < 13824) {
        int e = gid - 12544;
        int co = e / 20, k = e - co * 20;
        t1[co*32 + 12 + k] = 0;
    } else if (gid < 13888) {
        int o = gid - 13824;
        float s = ldany(g1, o, isf32) * rsqrtf(ldany(v1, o, isf32) + 1e-3f);
        wsf[OFF_B1 + o] = (ldany(b1, o, isf32) - ldany(m1, o, isf32)) * s + ldany(be1, o, isf32);
    } else if (gid < 13952) {
        int o = gid - 13888;
        float s = ldany(g2, o, isf32) * rsqrtf(ldany(v2, o, isf32) + 1e-3f);
        wsf[OFF_B2 + o] = (ldany(b2, o, isf32) - ldany(m2, o, isf32)) * s + ldany(be2, o, isf32);
    } else if (gid < 14080) {
        int o = gid - 13952;
        float s = ldany(g3, o, isf32) * rsqrtf(ldany(v3, o, isf32) + 1e-3f);
        wsf[OFF_B3 + o] = (ldany(b3, o, isf32) - ldany(m3, o, isf32)) * s + ldany(be3, o, isf32);
    }
}

// ---- one-target exact top-32 (R16-proven) + seeded first probe ----
__device__ __forceinline__ void knn_target(const void* p, long base, int isf32, int lane,
                                           float qx, float qy, float qz, float s1,
                                           unsigned long long* sl, uint16_t* dst) {
    uint32_t kb[32];
    if (!isf32) {
        const uint16_t* tpu = (const uint16_t*)p + base;
        const uint4* rx = (const uint4*)(tpu);
        const uint4* ry = (const uint4*)(tpu + NN);
        const uint4* rz = (const uint4*)(tpu + 2*NN);
        #pragma unroll
        for (int i = 0; i < 4; i++) {
            int v4 = i * 64 + lane;
            uint4 X = rx[v4], Y = ry[v4], Z = rz[v4];
            uint32_t xw[4] = {X.x, X.y, X.z, X.w};
            uint32_t yw[4] = {Y.x, Y.y, Y.z, Y.w};
            uint32_t zw[4] = {Z.x, Z.y, Z.z, Z.w};
            #pragma unroll
            for (int j = 0; j < 4; j++) {
                #pragma unroll
                for (int w = 0; w < 2; w++) {
                    uint32_t ux = (w == 0) ? (xw[j] << 16) : (xw[j] & 0xFFFF0000u);
                    uint32_t uy = (w == 0) ? (yw[j] << 16) : (yw[j] & 0xFFFF0000u);
                    uint32_t uz = (w == 0) ? (zw[j] << 16) : (zw[j] & 0xFFFF0000u);
                    float nx, ny, nz;
                    __builtin_memcpy(&nx, &ux, 4); __builtin_memcpy(&ny, &uy, 4); __builtin_memcpy(&nz, &uz, 4);
                    float s2  = nx * nx + ny * ny + nz * nz;
                    float dot = qx * nx + qy * ny + qz * nz;
                    float d2  = fmaxf((s1 + s2) - 2.0f * dot, 0.0f);
                    uint32_t bits; __builtin_memcpy(&bits, &d2, 4);
                    kb[i*8 + j*2 + w] = bits;
                }
            }
        }
    } else {
        const float* tpf = (const float*)p + base;
        #pragma unroll
        for (int i = 0; i < 32; i++) {
            int j = i * 64 + lane;
            float nx = tpf[j];
            float ny = tpf[NN + j];
            float nz = tpf[2*NN + j];
            float s2  = nx * nx + ny * ny + nz * nz;
            float dot = qx * nx + qy * ny + qz * nz;
            float d2  = fmaxf((s1 + s2) - 2.0f * dot, 0.0f);
            uint32_t bits; __builtin_memcpy(&bits, &d2, 4);
            kb[i] = bits;
        }
    }

    // windowed bisection, first probe seeded at 0.25f (typical top-32 radius^2 for N(0,1)^3).
    // Output set is tau-independent for any tau with count in [32,64] -> bit-identical result.
    uint32_t lo = 0u, hi = 0x7F800001u, tau = 0u;
    uint32_t mid = 0x3E800000u;   // 0.25f
    while (true) {
        int c = 0;
        #pragma unroll
        for (int i = 0; i < 32; i++) c += __builtin_popcountll(__ballot(kb[i] < mid));
        if (c < 32)      lo = mid;
        else if (c > 64) hi = mid;
        else { tau = mid; break; }
        if (hi - lo <= 1u) { tau = hi; break; }
        mid = lo + ((hi - lo) >> 1);
    }

    sl[lane] = ~0ull;
    int basePos = 0;
    #pragma unroll
    for (int i = 0; i < 32; i++) {
        unsigned idxv = isf32 ? (unsigned)(i * 64 + lane)
                              : (unsigned)((i >> 3) * 512 + 8 * lane + (i & 7));
        bool pz = kb[i] < tau;
        unsigned long long m = __ballot(pz);
        int pos = basePos + mbcnt64(m);
        if (pz && pos < 64) sl[pos] = (((unsigned long long)kb[i]) << 32) | idxv;
        basePos += __builtin_popcountll(m);
    }
    unsigned long long key = sl[lane];

    #pragma unroll
    for (int sz = 2; sz <= 64; sz <<= 1) {
        #pragma unroll
        for (int st = sz >> 1; st > 0; st >>= 1) {
            unsigned long long ot = __shfl_xor(key, st, 64);
            bool up    = ((lane & sz) == 0);
            bool lower = ((lane & st) == 0);
            unsigned long long mn = (key < ot) ? key : ot;
            unsigned long long mx = (key < ot) ? ot : key;
            key = (lower == up) ? mn : mx;
        }
    }

    if (lane < 32) dst[lane] = (uint16_t)(key & 0x7FFu);
}

// ---------------- K1: dual-target top-32 — two sequential phases (R16-proven) ----------------
__launch_bounds__(256)
__global__ void k1_knn(const void* p1, const void* p2, const int* wsi, uint16_t* idxout) {
    __shared__ unsigned long long smem[4 * 64];

    int isf32 = wsi[0];
    int lane = threadIdx.x & 63;
    int wave = threadIdx.x >> 6;
    int qidx = blockIdx.x * 4 + wave;
    int b = qidx >> 11, n = qidx & 2047;
    long base = (long)b * 3 * NN;

    float qx = ldany(p1, base + n,        isf32);
    float qy = ldany(p1, base + NN + n,   isf32);
    float qz = ldany(p1, base + 2*NN + n, isf32);
    float s1 = qx * qx + qy * qy + qz * qz;

    unsigned long long* sl = smem + wave * 64;
    long obase = ((long)qidx) << 6;

    knn_target(p1, base, isf32, lane, qx, qy, qz, s1, sl, idxout + obase);

    __builtin_amdgcn_sched_barrier(0);
    asm volatile("" ::: "memory");

    knn_target(p2, base, isf32, lane, qx, qy, qz, s1, sl, idxout + obase + 32);
}

// ---------------- K2: MFMA MLP — LDS-staged weights, 512-thread blocks (2 blocks/CU) ----------------
__launch_bounds__(512)
__global__ void k2_mlp(const void* p1, const void* p2, const float* __restrict__ wsf, const int* wsi,
                       const uint16_t* __restrict__ idxin, void* outp) {
    __shared__ uint4 shw4[L_HALVES / 8];

    {
        const uint4* src = (const uint4*)((const char*)wsf + T1_OFF);
        for (int i = threadIdx.x; i < L_HALVES / 8; i += 512) shw4[i] = src[i];
    }
    __syncthreads();
    const uint16_t* shw = (const uint16_t*)shw4;
    const uint16_t* T1  = shw + L_T1;
    const uint16_t* T2H = shw + L_T2H;
    const uint16_t* T2L = shw + L_T2L;
    const uint16_t* T3H = shw + L_T3H;
    const uint16_t* T3L = shw + L_T3L;

    int isf32 = wsi[0];
    int lane = threadIdx.x & 63;
    int wave = threadIdx.x >> 6;        // 0..7
    int c = lane & 15;
    int q = lane >> 4;
    int qidx = blockIdx.x * 8 + wave;   // 2048 blocks x 8 waves = 16384 queries
    int b = qidx >> 11, n = qidx & 2047;
    long base = (long)b * 3 * NN;

    float qx = sane(ldany(p1, base + n,        isf32));
    float qy = sane(ldany(p1, base + NN + n,   isf32));
    float qz = sane(ldany(p1, base + 2*NN + n, isf32));

    int idx = idxin[((long)qidx << 6) + lane] & 2047;
    const void* sp = (lane < 32) ? p1 : p2;
    float nx = sane(ldany(sp, base + idx,        isf32));
    float ny = sane(ldany(sp, base + NN + idx,   isf32));
    float nz = sane(ldany(sp, base + 2*NN + idx, isf32));

    float r0 = nx - qx, r1 = ny - qy, r2 = nz - qz;
    float ss = fmaf(r0, r0, fmaf(r1, r1, r2 * r2));
    float dist = sqrtf(fmaxf(ss, 1e-12f));

    const float* B1 = wsf + OFF_B1;
    const float* B2 = wsf + OFF_B2;
    const float* B3 = wsf + OFF_B3;

    s16x8 b1f[4];
    #pragma unroll
    for (int nt = 0; nt < 4; nt++) {
        int src = 16 * nt + c;
        float f0 = __shfl(r0, src, 64);
        float f1 = __shfl(r1, src, 64);
        float f2v = __shfl(r2, src, 64);
        float f3v = __shfl(dist, src, 64);
        uint16_t h0 = f2bf(f0), h1 = f2bf(f1), h2 = f2bf(f2v), h3 = f2bf(f3v);
        uint16_t l0 = f2bf(f0 - bf2f(h0)), l1 = f2bf(f1 - bf2f(h1));
        uint16_t l2 = f2bf(f2v - bf2f(h2)), l3 = f2bf(f3v - bf2f(h3));
        s16x8 v;
        bool qa = (q < 2);
        bool qb = (q == 0);
        v[0] = qa ? (short)h0 : (short)0;
        v[1] = qa ? (short)h1 : (short)0;
        v[2] = qa ? (short)h2 : (short)0;
        v[3] = qa ? (short)h3 : (short)0;
        v[4] = qb ? (short)l0 : (short)0;
        v[5] = qb ? (short)l1 : (short)0;
        v[6] = qb ? (short)l2 : (short)0;
        v[7] = qb ? (short)l3 : (short)0;
        b1f[nt] = v;
    }

    f32x4 d1[4][4];
    #pragma unroll
    for (int mt = 0; mt < 4; mt++) {
        s16x8 a1 = *(const s16x8*)(T1 + (16 * mt + c) * 32 + q * 8);
        f32x4 bias = *(const f32x4*)(B1 + 16 * mt + 4 * q);
        #pragma unroll
        for (int nt = 0; nt < 4; nt++) {
            d1[mt][nt] = __builtin_amdgcn_mfma_f32_16x16x32_bf16(a1, b1f[nt], bias, 0, 0, 0);
        }
    }

    auto mkfrag = [](const f32x4& dlo, const f32x4& dhi) -> s16x8 {
        return mk8(pk2(fmaxf(dlo[0], 0.f), fmaxf(dlo[1], 0.f)),
                   pk2(fmaxf(dlo[2], 0.f), fmaxf(dlo[3], 0.f)),
                   pk2(fmaxf(dhi[0], 0.f), fmaxf(dhi[1], 0.f)),
                   pk2(fmaxf(dhi[2], 0.f), fmaxf(dhi[3], 0.f)));
    };

    f32x4 d2[4][4];
    #pragma unroll
    for (int mt = 0; mt < 4; mt++) {
        f32x4 bias = *(const f32x4*)(B2 + 16 * mt + 4 * q);
        #pragma unroll
        for (int nt = 0; nt < 4; nt++) d2[mt][nt] = bias;
    }
    #pragma unroll
    for (int g = 0; g < 2; g++) {
        s16x8 fh[4];
        #pragma unroll
        for (int nt = 0; nt < 4; nt++) fh[nt] = mkfrag(d1[2*g][nt], d1[2*g+1][nt]);
        #pragma unroll
        for (int mt = 0; mt < 4; mt++) {
            s16x8 ah = *(const s16x8*)(T2H + (16 * mt + c) * 72 + 32 * g + 8 * q);
            s16x8 al = *(const s16x8*)(T2L + (16 * mt + c) * 72 + 32 * g + 8 * q);
            #pragma unroll
            for (int nt = 0; nt < 4; nt++) {
                f32x4 acc = d2[mt][nt];
                acc = __builtin_amdgcn_mfma_f32_16x16x32_bf16(ah, fh[nt], acc, 0, 0, 0);
                acc = __builtin_amdgcn_mfma_f32_16x16x32_bf16(al, fh[nt], acc, 0, 0, 0);
                d2[mt][nt] = acc;
            }
        }
    }

    s16x8 f3h[2][4];
    #pragma unroll
    for (int g = 0; g < 2; g++)
        #pragma unroll
        for (int nt = 0; nt < 4; nt++) f3h[g][nt] = mkfrag(d2[2*g][nt], d2[2*g+1][nt]);

    float mx[4] = {-1e30f, -1e30f, -1e30f, -1e30f};
    #pragma unroll
    for (int mt = 0; mt < 8; mt++) {
        f32x4 bias = *(const f32x4*)(B3 + 16 * mt + 4 * q);
        f32x4 acc[4];
        #pragma unroll
        for (int nt = 0; nt < 4; nt++) acc[nt] = bias;
        #pragma unroll
        for (int g = 0; g < 2; g++) {
            s16x8 ah = *(const s16x8*)(T3H + (16 * mt + c) * 72 + 32 * g + 8 * q);
            s16x8 al = *(const s16x8*)(T3L + (16 * mt + c) * 72 + 32 * g + 8 * q);
            #pragma unroll
            for (int nt = 0; nt < 4; nt++) {
                f32x4 a = acc[nt];
                a = __builtin_amdgcn_mfma_f32_16x16x32_bf16(ah, f3h[g][nt], a, 0, 0, 0);
                a = __builtin_amdgcn_mfma_f32_16x16x32_bf16(al, f3h[g][nt], a, 0, 0, 0);
                acc[nt] = a;
            }
        }
        #pragma unroll
        for (int nt = 0; nt < 4; nt++) {
            mx[nt] = fmaxf(mx[nt], fmaxf(fmaxf(acc[nt][0], acc[nt][1]), fmaxf(acc[nt][2], acc[nt][3])));
        }
    }

    #pragma unroll
    for (int nt = 0; nt < 4; nt++) {
        mx[nt] = fmaxf(mx[nt], __shfl_xor(mx[nt], 16, 64));
        mx[nt] = fmaxf(mx[nt], __shfl_xor(mx[nt], 32, 64));
        mx[nt] = fmaxf(mx[nt], 0.f);
    }
    float mall = fmaxf(fmaxf(mx[0], mx[1]), fmaxf(mx[2], mx[3]));
    #pragma unroll
    for (int m = 1; m < 16; m <<= 1) mall = fmaxf(mall, __shfl_xor(mall, m, 64));
    float e0 = __expf(mx[0] - mall), e1 = __expf(mx[1] - mall);
    float e2 = __expf(mx[2] - mall), e3 = __expf(mx[3] - mall);
    float s = e0 + e1 + e2 + e3;
    #pragma unroll
    for (int m = 1; m < 16; m <<= 1) s += __shfl_xor(s, m, 64);
    float eown = (q == 0) ? e0 : (q == 1) ? e1 : (q == 2) ? e2 : e3;
    float w = eown / s;

    float sx = w * nx, sy = w * ny, sz = w * nz;
    #pragma unroll
    for (int m = 1; m < 64; m <<= 1) {
        sx += __shfl_xor(sx, m, 64);
        sy += __shfl_xor(sy, m, 64);
        sz += __shfl_xor(sz, m, 64);
    }

    if (lane < 3) {
        float v = (lane == 0) ? sx : ((lane == 1) ? sy : sz);
        long oi = base + (long)lane * NN + n;
        if (isf32) {
            ((float*)outp)[oi] = v;
        } else {
            ((uint16_t*)outp)[oi] = f2bf(v);
        }
    }
}

extern "C" void kernel_launch(void* const* d_in, const int* in_sizes, int n_in,
                              void* d_out, int out_size, void* d_ws, size_t ws_size,
                              hipStream_t stream) {
    const void* p1 = d_in[0];
    const void* p2 = d_in[1];
    float* wsf = (float*)d_ws;
    int*   wsi = (int*)d_ws;
    uint16_t* idxbuf = (uint16_t*)((char*)d_ws + IDX_BYTE_OFF);

    k0_fold<<<64, 256, 0, stream>>>(p1,
        d_in[2],  d_in[3],  d_in[4],  d_in[5],  d_in[6],  d_in[7],
        d_in[8],  d_in[9],  d_in[10], d_in[11], d_in[12], d_in[13],
        d_in[14], d_in[15], d_in[16], d_in[17], d_in[18], d_in[19],
        wsf, wsi);

    k1_knn<<<(BB * NN) / 4, 256, 0, stream>>>(p1, p2, wsi, idxbuf);

    // 8 waves/block share one staged table copy; 2 blocks/CU: 2048 blocks
    k2_mlp<<<(BB * NN) / 8, 512, 0, stream>>>(p1, p2, wsf, wsi, idxbuf, d_out);
}